// Round 3
// baseline (272.406 us; speedup 1.0000x reference)
//
#include <hip/hip_runtime.h>
#include <math.h>

// Problem constants (x: [4, 64, 384, 384] fp32)
#define QLS_T   256            // B*C = 4*64, sequential scan axis
#define QLS_HW  (384 * 384)    // independent spatial locations
#define PF      16             // software-pipeline prefetch depth

// Quantizer constants from the reference
#define Q_SCALE      16.0f
#define INV_Q_SCALE  (1.0f / 16.0f)
#define QMAXF        7.9375f
#define QMINF        (-8.0f)
#define LUT_IN_SCALE 4096.0f
#define LUT_IN_MAX   32767.0f
#define INV_LUT_OUT  (1.0f / 65536.0f)

// log1p(exp(-d)) = log2(1 + 2^(-d*log2e)) * ln2 on raw v_exp_f32/v_log_f32.
#define NEG_LOG2E_DIV (-1.4426950408889634f / 4096.0f)
#define LN2_X_65536   45426.09375f

// R2 post-mortem: VGPR_Count=12 -> compiler serialized the loads
// (vmcnt(0) every step); 256 x (900cyc latency + 64cyc chain) = 103us,
// matching the measured 105us. Fix: explicit register prefetch buffers so
// 16 loads stay in flight while the serial scan chain consumes the
// previous 16. Pass 2 gets the same pipeline (L3-hit reads, NT stores).

__device__ __forceinline__ float qls_combine(float s, float v) {
    float diff  = fabsf(s - v);
    float d_int = fminf(floorf(diff * LUT_IN_SCALE), LUT_IN_MAX);
    float e     = __builtin_amdgcn_exp2f(d_int * NEG_LOG2E_DIV);
    float lu    = rintf(__builtin_amdgcn_logf(1.0f + e) * LN2_X_65536) * INV_LUT_OUT;
    return fminf(fmaxf(fmaxf(s, v) + lu, QMINF), QMAXF);
}

// One thread per spatial location: 2304 blocks x 64 = 9 waves/CU.
__global__ __launch_bounds__(64) void QuantizedLogSoftmax_12970801234623_kernel(
    const float* __restrict__ x, float* __restrict__ out) {
    const int i = blockIdx.x * 64 + threadIdx.x;   // spatial index in [0, HW)
    const float* xp = x + i;

    // ---- Pass 1: sequential quantized log-sum-exp scan, pipelined ----
    float s = QMINF;
    float vb[PF];
    #pragma unroll
    for (int j = 0; j < PF; ++j) vb[j] = xp[j * QLS_HW];

    for (int g = 0; g < QLS_T / PF - 1; ++g) {
        const float* np = xp + (g + 1) * PF * QLS_HW;
        float nb[PF];
        #pragma unroll
        for (int j = 0; j < PF; ++j) nb[j] = np[j * QLS_HW];   // issue next group
        #pragma unroll
        for (int j = 0; j < PF; ++j) s = qls_combine(s, vb[j]); // consume current
        #pragma unroll
        for (int j = 0; j < PF; ++j) vb[j] = nb[j];
    }
    #pragma unroll
    for (int j = 0; j < PF; ++j) s = qls_combine(s, vb[j]);     // tail group

    // ---- Pass 2: quantize x - s, pipelined (reads are L3 hits) ----
    float* op = out + i;
    #pragma unroll
    for (int j = 0; j < PF; ++j) vb[j] = xp[j * QLS_HW];

    for (int g = 0; g < QLS_T / PF - 1; ++g) {
        const float* np = xp + (g + 1) * PF * QLS_HW;
        float*       sp = op + g * PF * QLS_HW;
        float nb[PF];
        #pragma unroll
        for (int j = 0; j < PF; ++j) nb[j] = np[j * QLS_HW];
        #pragma unroll
        for (int j = 0; j < PF; ++j) {
            float q = fminf(fmaxf(rintf((vb[j] - s) * Q_SCALE), -128.0f), 127.0f);
            __builtin_nontemporal_store(q * INV_Q_SCALE, sp + j * QLS_HW);
        }
        #pragma unroll
        for (int j = 0; j < PF; ++j) vb[j] = nb[j];
    }
    float* sp = op + (QLS_T - PF) * QLS_HW;
    #pragma unroll
    for (int j = 0; j < PF; ++j) {
        float q = fminf(fmaxf(rintf((vb[j] - s) * Q_SCALE), -128.0f), 127.0f);
        __builtin_nontemporal_store(q * INV_Q_SCALE, sp + j * QLS_HW);
    }
}

extern "C" void kernel_launch(void* const* d_in, const int* in_sizes, int n_in,
                              void* d_out, int out_size, void* d_ws, size_t ws_size,
                              hipStream_t stream) {
    const float* x = (const float*)d_in[0];
    float* out = (float*)d_out;
    const int threads = 64;
    const int blocks = QLS_HW / threads;  // 2304
    QuantizedLogSoftmax_12970801234623_kernel<<<blocks, threads, 0, stream>>>(x, out);
}